// Round 1
// baseline (655.899 us; speedup 1.0000x reference)
//
#include <hip/hip_runtime.h>
#include <hip/hip_bf16.h>
#include <stdint.h>

#define D_DIM 1024
#define NNZ 64
#define RGRID 16
#define TM 32
#define THREADS 512
#define NTILES 2048  /* 65536 tokens / TM */

typedef __attribute__((ext_vector_type(8))) short short8;
typedef __attribute__((ext_vector_type(4))) float f32x4;

// ---- workspace layout ----
// [0, 524288)        : wbf   bf16[64][64][64]   (weights, row-major [n][k] per block)
// [524288, 528384)   : bias2 float[1024]        (bias gathered by out_perm)
// [528384, 528448)   : row_cnt int[16]
// [528448, 529472)   : row_data int[16][16]     ((block_idx<<4) | bcol)

#define WS_WBF 0
#define WS_BIAS2 524288
#define WS_RCNT 528384
#define WS_RDATA 528448

__device__ __forceinline__ unsigned short f2bf(float f) {
  unsigned u = __float_as_uint(f);
  u = (u + 0x7FFFu + ((u >> 16) & 1u)) >> 16;  // RNE
  return (unsigned short)u;
}
__device__ __forceinline__ float bf2f(unsigned short s) {
  return __uint_as_float(((unsigned)s) << 16);
}

__global__ void prep_kernel(const float* __restrict__ wblocks,
                            const int* __restrict__ brow,
                            const int* __restrict__ bcol,
                            const int* __restrict__ out_perm,
                            const float* __restrict__ bias,
                            unsigned char* __restrict__ ws) {
  if (blockIdx.x == 0) {
    float* bias2 = (float*)(ws + WS_BIAS2);
    for (int j = threadIdx.x; j < D_DIM; j += blockDim.x)
      bias2[j] = bias[out_perm[j]];
    if (threadIdx.x == 0) {
      int* row_cnt = (int*)(ws + WS_RCNT);
      int* row_data = (int*)(ws + WS_RDATA);
      int cnt[RGRID];
      for (int r = 0; r < RGRID; ++r) cnt[r] = 0;
      for (int b = 0; b < NNZ; ++b) {
        int r = brow[b];
        row_data[(r << 4) + cnt[r]] = (b << 4) | bcol[b];
        cnt[r]++;
      }
      for (int r = 0; r < RGRID; ++r) row_cnt[r] = cnt[r];
    }
  } else {
    int b = blockIdx.x - 1;  // 0..63: convert one 64x64 block fp32 -> bf16
    const float* src = wblocks + (size_t)b * 4096;
    unsigned short* dst = (unsigned short*)(ws + WS_WBF) + (size_t)b * 4096;
    for (int k = threadIdx.x * 4; k < 4096; k += blockDim.x * 4) {
      float4 v = *(const float4*)(src + k);
      ushort4 o;
      o.x = f2bf(v.x); o.y = f2bf(v.y); o.z = f2bf(v.z); o.w = f2bf(v.w);
      *(ushort4*)(dst + k) = o;
    }
  }
}

// LDS tile: 32 rows x 2048 bytes (1024 bf16), XOR-swizzled: byte ^= (t&15)<<4.
// Aliased: xg (gathered bf16 x) during compute, y (bf16) during epilogue.
__global__ __launch_bounds__(THREADS, 4)
void bsl_main(const float* __restrict__ x,
              const int* __restrict__ in_perm,
              const int* __restrict__ out_perm,
              const unsigned char* __restrict__ ws,
              float* __restrict__ out) {
  __shared__ unsigned char lds[TM * 2048];

  const unsigned short* wbf = (const unsigned short*)(ws + WS_WBF);
  const float* bias2 = (const float*)(ws + WS_BIAS2);
  const int* row_cnt = (const int*)(ws + WS_RCNT);
  const int* row_data = (const int*)(ws + WS_RDATA);

  const int tid = threadIdx.x;
  const int lane = tid & 63;
  const int wv = tid >> 6;        // wave 0..7
  const int t = tid >> 4;         // staging/gather row 0..31
  const int i0 = (tid & 15) * 4;  // 4 consecutive columns per thread per chunk
  const size_t row0 = (size_t)blockIdx.x * TM;

  const unsigned rowbase = (unsigned)t * 2048u;
  const unsigned swz = ((unsigned)t & 15u) << 4;

  // ---- stage: gather x[t][in_perm[i]] -> bf16 LDS tile ----
  {
    const float* xrow = x + (row0 + (unsigned)t) * D_DIM;
    #pragma unroll 4
    for (int c = 0; c < 16; ++c) {
      const int i = i0 + (c << 6);
      const int4 p = *(const int4*)(in_perm + i);
      ushort4 pk;
      pk.x = f2bf(xrow[p.x]);
      pk.y = f2bf(xrow[p.y]);
      pk.z = f2bf(xrow[p.z]);
      pk.w = f2bf(xrow[p.w]);
      *(ushort4*)(lds + rowbase + (((unsigned)(i * 2)) ^ swz)) = pk;
    }
  }
  __syncthreads();

  // ---- block-sparse MFMA: wave wv handles block-rows wv and wv+8 ----
  f32x4 acc[2][2][4];
  {
    const f32x4 z = {0.0f, 0.0f, 0.0f, 0.0f};
    #pragma unroll
    for (int a1 = 0; a1 < 2; ++a1)
      #pragma unroll
      for (int a2 = 0; a2 < 2; ++a2)
        #pragma unroll
        for (int a3 = 0; a3 < 4; ++a3)
          acc[a1][a2][a3] = z;
  }

  const int hi = lane >> 4;  // 0..3
  const int lo = lane & 15;  // 0..15
  const unsigned aswz = ((unsigned)lo & 15u) << 4;  // == swz for rows lo and lo+16

  #pragma unroll
  for (int rr = 0; rr < 2; ++rr) {
    const int r = wv + (rr << 3);
    const int cnt = row_cnt[r];
    for (int ci = 0; ci < cnt; ++ci) {
      const int e = row_data[(r << 4) + ci];
      const int bidx = e >> 4;
      const int bc = e & 15;
      const unsigned short* wb = wbf + (bidx << 12);
      #pragma unroll
      for (int ks = 0; ks < 2; ++ks) {
        // A fragments: xg[16*mf + lo][bc*64 + ks*32 + hi*8 .. +8)
        const unsigned colbyte = (unsigned)((bc << 7) + (ks << 6) + (hi << 4));
        const short8 a0 = *(const short8*)(lds + (unsigned)lo * 2048u + (colbyte ^ aswz));
        const short8 a1 = *(const short8*)(lds + ((unsigned)lo + 16u) * 2048u + (colbyte ^ aswz));
        #pragma unroll
        for (int nf = 0; nf < 4; ++nf) {
          // B fragment: blk[n = lo+16*nf][k = ks*32 + hi*8 .. +8)  (row-major [64][64])
          const short8 bfr = *(const short8*)(wb + ((lo + (nf << 4)) << 6) + (ks << 5) + (hi << 3));
          acc[rr][0][nf] = __builtin_amdgcn_mfma_f32_16x16x32_bf16(a0, bfr, acc[rr][0][nf], 0, 0, 0);
          acc[rr][1][nf] = __builtin_amdgcn_mfma_f32_16x16x32_bf16(a1, bfr, acc[rr][1][nf], 0, 0, 0);
        }
      }
    }
  }
  __syncthreads();  // all xg reads done; LDS can be re-used for y

  // ---- write y tile (bf16) into aliased LDS; D-layout: row=(hi*4+reg)+16*mf, col=lo ----
  #pragma unroll
  for (int rr = 0; rr < 2; ++rr) {
    const int r = wv + (rr << 3);
    #pragma unroll
    for (int mf = 0; mf < 2; ++mf)
      #pragma unroll
      for (int nf = 0; nf < 4; ++nf)
        #pragma unroll
        for (int reg = 0; reg < 4; ++reg) {
          const int t2 = (hi << 2) + reg + (mf << 4);
          const int o = lo + (nf << 4) + (r << 6);
          *(unsigned short*)(lds + (unsigned)t2 * 2048u +
                             (((unsigned)(o * 2)) ^ (((unsigned)t2 & 15u) << 4))) =
              f2bf(acc[rr][mf][nf][reg]);
        }
  }
  __syncthreads();

  // ---- epilogue: out[t][j] = y[t][out_perm[j]] + bias2[j], coalesced float4 stores ----
  {
    float* orow = out + (row0 + (unsigned)t) * D_DIM;
    #pragma unroll 4
    for (int c = 0; c < 16; ++c) {
      const int j = i0 + (c << 6);
      const int4 op = *(const int4*)(out_perm + j);
      const float4 b2 = *(const float4*)(bias2 + j);
      float4 o4;
      o4.x = bf2f(*(const unsigned short*)(lds + rowbase + (((unsigned)(op.x * 2)) ^ swz))) + b2.x;
      o4.y = bf2f(*(const unsigned short*)(lds + rowbase + (((unsigned)(op.y * 2)) ^ swz))) + b2.y;
      o4.z = bf2f(*(const unsigned short*)(lds + rowbase + (((unsigned)(op.z * 2)) ^ swz))) + b2.z;
      o4.w = bf2f(*(const unsigned short*)(lds + rowbase + (((unsigned)(op.w * 2)) ^ swz))) + b2.w;
      *(float4*)(orow + j) = o4;
    }
  }
}

extern "C" void kernel_launch(void* const* d_in, const int* in_sizes, int n_in,
                              void* d_out, int out_size, void* d_ws, size_t ws_size,
                              hipStream_t stream) {
  const float* x = (const float*)d_in[0];
  const int* in_perm = (const int*)d_in[1];
  const int* out_perm = (const int*)d_in[2];
  const float* wblocks = (const float*)d_in[3];
  const int* brow = (const int*)d_in[4];
  const int* bcol = (const int*)d_in[5];
  const float* bias = (const float*)d_in[6];
  float* out = (float*)d_out;
  unsigned char* ws = (unsigned char*)d_ws;

  prep_kernel<<<65, 256, 0, stream>>>(wblocks, brow, bcol, out_perm, bias, ws);
  bsl_main<<<NTILES, THREADS, 0, stream>>>(x, in_perm, out_perm, ws, out);
}

// Round 2
// 627.996 us; speedup vs baseline: 1.0444x; 1.0444x over previous
//
#include <hip/hip_runtime.h>
#include <hip/hip_bf16.h>
#include <stdint.h>

#define D_DIM 1024
#define NNZ 64
#define RGRID 16
#define TM 32
#define THREADS 512
#define NTILES 2048  /* 65536 tokens / TM */

typedef __attribute__((ext_vector_type(8))) short short8;
typedef __attribute__((ext_vector_type(4))) float f32x4;

// ---- workspace layout ----
#define WS_WBF 0
#define WS_BIAS2 524288
#define WS_RCNT 528384
#define WS_RDATA 528448

__device__ __forceinline__ unsigned short f2bf(float f) {
  __hip_bfloat16 h = __float2bfloat16(f);
  return *reinterpret_cast<unsigned short*>(&h);
}
__device__ __forceinline__ float bf2f(unsigned short s) {
  return __uint_as_float(((unsigned)s) << 16);
}

__global__ void prep_kernel(const float* __restrict__ wblocks,
                            const int* __restrict__ brow,
                            const int* __restrict__ bcol,
                            const int* __restrict__ out_perm,
                            const float* __restrict__ bias,
                            unsigned char* __restrict__ ws) {
  if (blockIdx.x == 0) {
    float* bias2 = (float*)(ws + WS_BIAS2);
    for (int j = threadIdx.x; j < D_DIM; j += blockDim.x)
      bias2[j] = bias[out_perm[j]];
    if (threadIdx.x == 0) {
      int* row_cnt = (int*)(ws + WS_RCNT);
      int* row_data = (int*)(ws + WS_RDATA);
      int cnt[RGRID];
      for (int r = 0; r < RGRID; ++r) cnt[r] = 0;
      for (int b = 0; b < NNZ; ++b) {
        int r = brow[b];
        row_data[(r << 4) + cnt[r]] = (b << 4) | bcol[b];
        cnt[r]++;
      }
      for (int r = 0; r < RGRID; ++r) row_cnt[r] = cnt[r];
    }
  } else {
    int b = blockIdx.x - 1;  // 0..63: convert one 64x64 block fp32 -> bf16
    const float* src = wblocks + (size_t)b * 4096;
    unsigned short* dst = (unsigned short*)(ws + WS_WBF) + (size_t)b * 4096;
    for (int k = threadIdx.x * 4; k < 4096; k += blockDim.x * 4) {
      float4 v = *(const float4*)(src + k);
      ushort4 o;
      o.x = f2bf(v.x); o.y = f2bf(v.y); o.z = f2bf(v.z); o.w = f2bf(v.w);
      *(ushort4*)(dst + k) = o;
    }
  }
}

// LDS: [0,65536)  xg bf16[32][1024], rows swizzled: byte ^= (row&15)<<4
//      [65536,81920) xraw fp32[4][1024] staging strip (4 rows at a time)
// xg region is re-used for the bf16 y tile in the epilogue.
__global__ __launch_bounds__(THREADS, 4)
void bsl_main(const float* __restrict__ x,
              const int* __restrict__ in_perm,
              const int* __restrict__ out_perm,
              const unsigned char* __restrict__ ws,
              float* __restrict__ out) {
  __shared__ unsigned char lds[TM * 2048 + 16384];
  float* xraw = (float*)(lds + TM * 2048);

  const unsigned short* wbf = (const unsigned short*)(ws + WS_WBF);
  const float* bias2 = (const float*)(ws + WS_BIAS2);
  const int* row_cnt = (const int*)(ws + WS_RCNT);
  const int* row_data = (const int*)(ws + WS_RDATA);

  const int tid = threadIdx.x;
  const int lane = tid & 63;
  const int wv = tid >> 6;        // wave 0..7
  const int t = tid >> 4;         // epilogue row 0..31
  const int i0 = (tid & 15) * 4;  // epilogue 4-col chunk base
  const size_t row0 = (size_t)blockIdx.x * TM;

  // ---- gather thread mapping: strip-row rloc, 8 consecutive xg columns j0..j0+7
  const int rloc = tid >> 7;       // 0..3 (whole wave shares one row)
  const int j0 = (tid & 127) * 8;  // 0..1016
  const int4 pA = *(const int4*)(in_perm + j0);
  const int4 pB = *(const int4*)(in_perm + j0 + 4);

  // ---- staged gather: 8 strips of 4 rows, reg-staged (issue-early/write-late)
  {
    const float* xq = x + row0 * D_DIM;
    float4 r0 = *(const float4*)(xq + tid * 4);
    float4 r1 = *(const float4*)(xq + tid * 4 + 2048);
    const float* xr = xraw + (rloc << 10);
    #pragma unroll 1
    for (int q = 0; q < 8; ++q) {
      ((float4*)xraw)[tid] = r0;
      ((float4*)xraw)[tid + 512] = r1;
      if (q < 7) {
        r0 = *(const float4*)(xq + (q + 1) * 4096 + tid * 4);
        r1 = *(const float4*)(xq + (q + 1) * 4096 + tid * 4 + 2048);
      }
      __syncthreads();
      // gather 8 columns of row (4q + rloc) from the fp32 strip
      const int row4 = (q << 2) + rloc;
      const unsigned swz = ((unsigned)row4 & 15u) << 4;
      float v0 = xr[pA.x], v1 = xr[pA.y], v2 = xr[pA.z], v3 = xr[pA.w];
      float v4 = xr[pB.x], v5 = xr[pB.y], v6 = xr[pB.z], v7 = xr[pB.w];
      uint4 pk;
      pk.x = (unsigned)f2bf(v0) | ((unsigned)f2bf(v1) << 16);
      pk.y = (unsigned)f2bf(v2) | ((unsigned)f2bf(v3) << 16);
      pk.z = (unsigned)f2bf(v4) | ((unsigned)f2bf(v5) << 16);
      pk.w = (unsigned)f2bf(v6) | ((unsigned)f2bf(v7) << 16);
      *(uint4*)(lds + (unsigned)row4 * 2048u + (((unsigned)(j0 * 2)) ^ swz)) = pk;
      __syncthreads();
    }
  }

  // ---- block-sparse MFMA: wave wv handles block-rows wv and wv+8 ----
  f32x4 acc[2][2][4];
  {
    const f32x4 z = {0.0f, 0.0f, 0.0f, 0.0f};
    #pragma unroll
    for (int a1 = 0; a1 < 2; ++a1)
      #pragma unroll
      for (int a2 = 0; a2 < 2; ++a2)
        #pragma unroll
        for (int a3 = 0; a3 < 4; ++a3)
          acc[a1][a2][a3] = z;
  }

  const int hi = lane >> 4;  // 0..3
  const int lo = lane & 15;  // 0..15
  const unsigned aswz = ((unsigned)lo & 15u) << 4;  // == row swizzle for rows lo, lo+16

  #pragma unroll
  for (int rr = 0; rr < 2; ++rr) {
    const int r = wv + (rr << 3);
    const int cnt = row_cnt[r];
    for (int ci = 0; ci < cnt; ++ci) {
      const int e = row_data[(r << 4) + ci];
      const int bidx = e >> 4;
      const int bc = e & 15;
      const unsigned short* wb = wbf + (bidx << 12);
      #pragma unroll
      for (int ks = 0; ks < 2; ++ks) {
        const unsigned colbyte = (unsigned)((bc << 7) + (ks << 6) + (hi << 4));
        const short8 a0 = *(const short8*)(lds + (unsigned)lo * 2048u + (colbyte ^ aswz));
        const short8 a1 = *(const short8*)(lds + ((unsigned)lo + 16u) * 2048u + (colbyte ^ aswz));
        #pragma unroll
        for (int nf = 0; nf < 4; ++nf) {
          const short8 bfr = *(const short8*)(wb + ((lo + (nf << 4)) << 6) + (ks << 5) + (hi << 3));
          acc[rr][0][nf] = __builtin_amdgcn_mfma_f32_16x16x32_bf16(a0, bfr, acc[rr][0][nf], 0, 0, 0);
          acc[rr][1][nf] = __builtin_amdgcn_mfma_f32_16x16x32_bf16(a1, bfr, acc[rr][1][nf], 0, 0, 0);
        }
      }
    }
  }
  __syncthreads();  // all xg reads done; LDS re-used for y

  // ---- write y tile (bf16) into aliased LDS; D-layout: row=(hi*4+reg)+16*mf, col=lo ----
  #pragma unroll
  for (int rr = 0; rr < 2; ++rr) {
    const int r = wv + (rr << 3);
    #pragma unroll
    for (int mf = 0; mf < 2; ++mf)
      #pragma unroll
      for (int nf = 0; nf < 4; ++nf)
        #pragma unroll
        for (int reg = 0; reg < 4; ++reg) {
          const int t2 = (hi << 2) + reg + (mf << 4);
          const int o = lo + (nf << 4) + (r << 6);
          *(unsigned short*)(lds + (unsigned)t2 * 2048u +
                             (((unsigned)(o * 2)) ^ (((unsigned)t2 & 15u) << 4))) =
              f2bf(acc[rr][mf][nf][reg]);
        }
  }
  __syncthreads();

  // ---- epilogue: out[t][j] = y[t][out_perm[j]] + bias2[j], coalesced float4 stores ----
  {
    const unsigned rowbase = (unsigned)t * 2048u;
    const unsigned swz = ((unsigned)t & 15u) << 4;
    float* orow = out + (row0 + (unsigned)t) * D_DIM;
    #pragma unroll 4
    for (int c = 0; c < 16; ++c) {
      const int j = i0 + (c << 6);
      const int4 op = *(const int4*)(out_perm + j);
      const float4 b2 = *(const float4*)(bias2 + j);
      float4 o4;
      o4.x = bf2f(*(const unsigned short*)(lds + rowbase + (((unsigned)(op.x * 2)) ^ swz))) + b2.x;
      o4.y = bf2f(*(const unsigned short*)(lds + rowbase + (((unsigned)(op.y * 2)) ^ swz))) + b2.y;
      o4.z = bf2f(*(const unsigned short*)(lds + rowbase + (((unsigned)(op.z * 2)) ^ swz))) + b2.z;
      o4.w = bf2f(*(const unsigned short*)(lds + rowbase + (((unsigned)(op.w * 2)) ^ swz))) + b2.w;
      *(float4*)(orow + j) = o4;
    }
  }
}

extern "C" void kernel_launch(void* const* d_in, const int* in_sizes, int n_in,
                              void* d_out, int out_size, void* d_ws, size_t ws_size,
                              hipStream_t stream) {
  const float* x = (const float*)d_in[0];
  const int* in_perm = (const int*)d_in[1];
  const int* out_perm = (const int*)d_in[2];
  const float* wblocks = (const float*)d_in[3];
  const int* brow = (const int*)d_in[4];
  const int* bcol = (const int*)d_in[5];
  const float* bias = (const float*)d_in[6];
  float* out = (float*)d_out;
  unsigned char* ws = (unsigned char*)d_ws;

  prep_kernel<<<65, 256, 0, stream>>>(wblocks, brow, bcol, out_perm, bias, ws);
  bsl_main<<<NTILES, THREADS, 0, stream>>>(x, in_perm, out_perm, ws, out);
}

// Round 3
// 616.574 us; speedup vs baseline: 1.0638x; 1.0185x over previous
//
#include <hip/hip_runtime.h>
#include <hip/hip_bf16.h>
#include <stdint.h>

#define D_DIM 1024
#define NNZ 64
#define RGRID 16
#define TM 32
#define THREADS 512
#define NTILES 2048  /* 65536 tokens / TM */

typedef __attribute__((ext_vector_type(8))) short short8;
typedef __attribute__((ext_vector_type(4))) float f32x4;

// ---- workspace layout ----
#define WS_WBF 0
#define WS_BIAS2 524288
#define WS_RCNT 528384
#define WS_RDATA 528448

__device__ __forceinline__ unsigned short f2bf(float f) {
  __hip_bfloat16 h = __float2bfloat16(f);
  return *reinterpret_cast<unsigned short*>(&h);
}
__device__ __forceinline__ float bf2f(unsigned short s) {
  return __uint_as_float(((unsigned)s) << 16);
}

__global__ void prep_kernel(const float* __restrict__ wblocks,
                            const int* __restrict__ brow,
                            const int* __restrict__ bcol,
                            const int* __restrict__ out_perm,
                            const float* __restrict__ bias,
                            unsigned char* __restrict__ ws) {
  if (blockIdx.x == 0) {
    float* bias2 = (float*)(ws + WS_BIAS2);
    for (int j = threadIdx.x; j < D_DIM; j += blockDim.x)
      bias2[j] = bias[out_perm[j]];
    if (threadIdx.x == 0) {
      int* row_cnt = (int*)(ws + WS_RCNT);
      int* row_data = (int*)(ws + WS_RDATA);
      int cnt[RGRID];
      for (int r = 0; r < RGRID; ++r) cnt[r] = 0;
      for (int b = 0; b < NNZ; ++b) {
        int r = brow[b];
        row_data[(r << 4) + cnt[r]] = (b << 4) | bcol[b];
        cnt[r]++;
      }
      for (int r = 0; r < RGRID; ++r) row_cnt[r] = cnt[r];
    }
  } else {
    int b = blockIdx.x - 1;  // 0..63: convert one 64x64 block fp32 -> bf16
    const float* src = wblocks + (size_t)b * 4096;
    unsigned short* dst = (unsigned short*)(ws + WS_WBF) + (size_t)b * 4096;
    for (int k = threadIdx.x * 4; k < 4096; k += blockDim.x * 4) {
      float4 v = *(const float4*)(src + k);
      ushort4 o;
      o.x = f2bf(v.x); o.y = f2bf(v.y); o.z = f2bf(v.z); o.w = f2bf(v.w);
      *(ushort4*)(dst + k) = o;
    }
  }
}

// LDS: [0,65536)  xg bf16[32][1024], rows swizzled: byte ^= (row&15)<<4
//      [65536,81920) xraw fp32[4][1024] staging strip (4 rows at a time)
// xg region is re-used for the bf16 y tile in the epilogue.
__global__ __launch_bounds__(THREADS, 4)
void bsl_main(const float* __restrict__ x,
              const int* __restrict__ in_perm,
              const int* __restrict__ out_perm,
              const unsigned char* __restrict__ ws,
              float* __restrict__ out) {
  __shared__ unsigned char lds[TM * 2048 + 16384];
  float* xraw = (float*)(lds + TM * 2048);

  const unsigned short* wbf = (const unsigned short*)(ws + WS_WBF);
  const float* bias2 = (const float*)(ws + WS_BIAS2);
  const int* row_cnt = (const int*)(ws + WS_RCNT);
  const int* row_data = (const int*)(ws + WS_RDATA);

  const int tid = threadIdx.x;
  const int lane = tid & 63;
  const int wv = tid >> 6;        // wave 0..7
  const int t = tid >> 4;         // epilogue row 0..31
  const int i0 = (tid & 15) * 4;  // epilogue 4-col chunk base
  const size_t row0 = (size_t)blockIdx.x * TM;

  // ---- gather thread mapping: strip-row rloc, 8 consecutive xg columns j0..j0+7
  const int rloc = tid >> 7;       // 0..3 (whole wave shares one row)
  const int j0 = (tid & 127) * 8;  // 0..1016
  const int4 pA = *(const int4*)(in_perm + j0);
  const int4 pB = *(const int4*)(in_perm + j0 + 4);

  // ---- stage: issue ALL 16 tile loads up-front (deep prefetch), then
  //      8x {LDS strip write -> barrier -> gather/convert -> barrier}
  {
    const float* xq = x + row0 * D_DIM;
    float4 ra0, ra1, ra2, ra3, ra4, ra5, ra6, ra7;
    float4 rb0, rb1, rb2, rb3, rb4, rb5, rb6, rb7;
    ra0 = *(const float4*)(xq + 0 * 4096 + tid * 4);
    rb0 = *(const float4*)(xq + 0 * 4096 + tid * 4 + 2048);
    ra1 = *(const float4*)(xq + 1 * 4096 + tid * 4);
    rb1 = *(const float4*)(xq + 1 * 4096 + tid * 4 + 2048);
    ra2 = *(const float4*)(xq + 2 * 4096 + tid * 4);
    rb2 = *(const float4*)(xq + 2 * 4096 + tid * 4 + 2048);
    ra3 = *(const float4*)(xq + 3 * 4096 + tid * 4);
    rb3 = *(const float4*)(xq + 3 * 4096 + tid * 4 + 2048);
    ra4 = *(const float4*)(xq + 4 * 4096 + tid * 4);
    rb4 = *(const float4*)(xq + 4 * 4096 + tid * 4 + 2048);
    ra5 = *(const float4*)(xq + 5 * 4096 + tid * 4);
    rb5 = *(const float4*)(xq + 5 * 4096 + tid * 4 + 2048);
    ra6 = *(const float4*)(xq + 6 * 4096 + tid * 4);
    rb6 = *(const float4*)(xq + 6 * 4096 + tid * 4 + 2048);
    ra7 = *(const float4*)(xq + 7 * 4096 + tid * 4);
    rb7 = *(const float4*)(xq + 7 * 4096 + tid * 4 + 2048);

    const float* xr = xraw + (rloc << 10);

#define DO_CHUNK(Q, RA, RB)                                                     \
    {                                                                           \
      ((float4*)xraw)[tid] = RA;                                                \
      ((float4*)xraw)[tid + 512] = RB;                                          \
      __syncthreads();                                                          \
      const int row4 = ((Q) << 2) + rloc;                                       \
      const unsigned swz = ((unsigned)row4 & 15u) << 4;                         \
      float v0 = xr[pA.x], v1 = xr[pA.y], v2 = xr[pA.z], v3 = xr[pA.w];         \
      float v4 = xr[pB.x], v5 = xr[pB.y], v6 = xr[pB.z], v7 = xr[pB.w];         \
      uint4 pk;                                                                 \
      pk.x = (unsigned)f2bf(v0) | ((unsigned)f2bf(v1) << 16);                   \
      pk.y = (unsigned)f2bf(v2) | ((unsigned)f2bf(v3) << 16);                   \
      pk.z = (unsigned)f2bf(v4) | ((unsigned)f2bf(v5) << 16);                   \
      pk.w = (unsigned)f2bf(v6) | ((unsigned)f2bf(v7) << 16);                   \
      *(uint4*)(lds + (unsigned)row4 * 2048u + (((unsigned)(j0 * 2)) ^ swz)) = pk; \
      __syncthreads();                                                          \
    }

    DO_CHUNK(0, ra0, rb0)
    DO_CHUNK(1, ra1, rb1)
    DO_CHUNK(2, ra2, rb2)
    DO_CHUNK(3, ra3, rb3)
    DO_CHUNK(4, ra4, rb4)
    DO_CHUNK(5, ra5, rb5)
    DO_CHUNK(6, ra6, rb6)
    DO_CHUNK(7, ra7, rb7)
#undef DO_CHUNK
  }

  // ---- block-sparse MFMA: wave wv handles block-rows wv and wv+8 ----
  f32x4 acc[2][2][4];
  {
    const f32x4 z = {0.0f, 0.0f, 0.0f, 0.0f};
    #pragma unroll
    for (int a1 = 0; a1 < 2; ++a1)
      #pragma unroll
      for (int a2 = 0; a2 < 2; ++a2)
        #pragma unroll
        for (int a3 = 0; a3 < 4; ++a3)
          acc[a1][a2][a3] = z;
  }

  const int hi = lane >> 4;  // 0..3
  const int lo = lane & 15;  // 0..15
  const unsigned aswz = ((unsigned)lo & 15u) << 4;  // == row swizzle for rows lo, lo+16

  #pragma unroll
  for (int rr = 0; rr < 2; ++rr) {
    const int r = wv + (rr << 3);
    const int cnt = row_cnt[r];
    for (int ci = 0; ci < cnt; ++ci) {
      const int e = row_data[(r << 4) + ci];
      const int bidx = e >> 4;
      const int bc = e & 15;
      const unsigned short* wb = wbf + (bidx << 12);
      #pragma unroll
      for (int ks = 0; ks < 2; ++ks) {
        const unsigned colbyte = (unsigned)((bc << 7) + (ks << 6) + (hi << 4));
        const short8 a0 = *(const short8*)(lds + (unsigned)lo * 2048u + (colbyte ^ aswz));
        const short8 a1 = *(const short8*)(lds + ((unsigned)lo + 16u) * 2048u + (colbyte ^ aswz));
        #pragma unroll
        for (int nf = 0; nf < 4; ++nf) {
          const short8 bfr = *(const short8*)(wb + ((lo + (nf << 4)) << 6) + (ks << 5) + (hi << 3));
          acc[rr][0][nf] = __builtin_amdgcn_mfma_f32_16x16x32_bf16(a0, bfr, acc[rr][0][nf], 0, 0, 0);
          acc[rr][1][nf] = __builtin_amdgcn_mfma_f32_16x16x32_bf16(a1, bfr, acc[rr][1][nf], 0, 0, 0);
        }
      }
    }
  }
  __syncthreads();  // all xg reads done; LDS re-used for y

  // ---- write y tile (bf16) into aliased LDS; D-layout: row=(hi*4+reg)+16*mf, col=lo ----
  #pragma unroll
  for (int rr = 0; rr < 2; ++rr) {
    const int r = wv + (rr << 3);
    #pragma unroll
    for (int mf = 0; mf < 2; ++mf)
      #pragma unroll
      for (int nf = 0; nf < 4; ++nf)
        #pragma unroll
        for (int reg = 0; reg < 4; ++reg) {
          const int t2 = (hi << 2) + reg + (mf << 4);
          const int o = lo + (nf << 4) + (r << 6);
          *(unsigned short*)(lds + (unsigned)t2 * 2048u +
                             (((unsigned)(o * 2)) ^ (((unsigned)t2 & 15u) << 4))) =
              f2bf(acc[rr][mf][nf][reg]);
        }
  }
  __syncthreads();

  // ---- epilogue: out[t][j] = y[t][out_perm[j]] + bias2[j], coalesced float4 stores ----
  {
    const unsigned rowbase = (unsigned)t * 2048u;
    const unsigned swz = ((unsigned)t & 15u) << 4;
    float* orow = out + (row0 + (unsigned)t) * D_DIM;
    #pragma unroll 4
    for (int c = 0; c < 16; ++c) {
      const int j = i0 + (c << 6);
      const int4 op = *(const int4*)(out_perm + j);
      const float4 b2 = *(const float4*)(bias2 + j);
      float4 o4;
      o4.x = bf2f(*(const unsigned short*)(lds + rowbase + (((unsigned)(op.x * 2)) ^ swz))) + b2.x;
      o4.y = bf2f(*(const unsigned short*)(lds + rowbase + (((unsigned)(op.y * 2)) ^ swz))) + b2.y;
      o4.z = bf2f(*(const unsigned short*)(lds + rowbase + (((unsigned)(op.z * 2)) ^ swz))) + b2.z;
      o4.w = bf2f(*(const unsigned short*)(lds + rowbase + (((unsigned)(op.w * 2)) ^ swz))) + b2.w;
      *(float4*)(orow + j) = o4;
    }
  }
}

extern "C" void kernel_launch(void* const* d_in, const int* in_sizes, int n_in,
                              void* d_out, int out_size, void* d_ws, size_t ws_size,
                              hipStream_t stream) {
  const float* x = (const float*)d_in[0];
  const int* in_perm = (const int*)d_in[1];
  const int* out_perm = (const int*)d_in[2];
  const float* wblocks = (const float*)d_in[3];
  const int* brow = (const int*)d_in[4];
  const int* bcol = (const int*)d_in[5];
  const float* bias = (const float*)d_in[6];
  float* out = (float*)d_out;
  unsigned char* ws = (unsigned char*)d_ws;

  prep_kernel<<<65, 256, 0, stream>>>(wblocks, brow, bcol, out_perm, bias, ws);
  bsl_main<<<NTILES, THREADS, 0, stream>>>(x, in_perm, out_perm, ws, out);
}

// Round 4
// 549.447 us; speedup vs baseline: 1.1937x; 1.1222x over previous
//
#include <hip/hip_runtime.h>
#include <hip/hip_bf16.h>
#include <stdint.h>

#define D_DIM 1024
#define NNZ 64
#define TM 64            /* tokens per WG */
#define THREADS 512
#define NTILES 1024      /* 65536 / TM */
#define LDS_BYTES 131072 /* 64 rows x 2048 B bf16, XOR-swizzled */

typedef __attribute__((ext_vector_type(8))) short short8;
typedef __attribute__((ext_vector_type(4))) float f32x4;

// ---- workspace layout ----
// [0, 2097152)       wq bf16, FRAGMENT-MAJOR:
//   16B unit index = ((ob*32 + ks)*4 + nf)*64 + lane,  lane = hi*16+lo
//   holds Wq[col = ob*64 + nf*16 + lo][k = ks*32 + hi*8 .. +8)
// [2097152, 2101248) bias2 float[1024]
#define WS_WQ 0
#define WS_BIAS2 2097152

__device__ __forceinline__ unsigned short f2bf(float f) {
  unsigned u = __float_as_uint(f);
  u = (u + 0x7FFFu + ((u >> 16) & 1u)) >> 16;  // RNE
  return (unsigned short)u;
}

// One WG per output row j: build Wq row via LDS scatter-add, emit fragments.
__global__ void prep_wq(const float* __restrict__ wblocks,
                        const int* __restrict__ brow,
                        const int* __restrict__ bcol,
                        const int* __restrict__ in_perm,
                        const int* __restrict__ out_perm,
                        const float* __restrict__ bias,
                        unsigned char* __restrict__ ws) {
  __shared__ float lrow[D_DIM];
  __shared__ int blk_b[16];
  __shared__ int blk_c[16];
  __shared__ int nblk_s;

  const int j = blockIdx.x;     // output row 0..1023
  const int tid = threadIdx.x;  // 256 threads
  const int po = out_perm[j];
  const int r = po >> 6;        // source block-row
  const int jj = po & 63;       // row within block

  for (int i = tid; i < D_DIM; i += 256) lrow[i] = 0.0f;
  if (tid == 0) {
    ((float*)(ws + WS_BIAS2))[j] = bias[po];
    int n = 0;
    for (int b = 0; b < NNZ; ++b)
      if (brow[b] == r) { blk_b[n] = b; blk_c[n] = bcol[b]; ++n; }
    nblk_s = n;
  }
  __syncthreads();

  const int n = nblk_s;
  for (int bi = 0; bi < n; ++bi) {
    if (tid < 64) {
      const float v = wblocks[(size_t)blk_b[bi] * 4096 + jj * 64 + tid];
      const int col = in_perm[blk_c[bi] * 64 + tid];
      atomicAdd(&lrow[col], v);  // in_perm may repeat -> accumulate
    }
  }
  __syncthreads();

  // fragment-major write: this row j owns (ob, nf, lo); cover all (ks, hi)
  const int ob = j >> 6, nf = (j >> 4) & 3, lo = j & 15;
  unsigned short* wq = (unsigned short*)(ws + WS_WQ);
  for (int u = tid; u < 128; u += 256) {
    const int ks = u >> 2, hi = u & 3;
    const float* s = lrow + ks * 32 + hi * 8;
    uint4 pk;
    pk.x = (unsigned)f2bf(s[0]) | ((unsigned)f2bf(s[1]) << 16);
    pk.y = (unsigned)f2bf(s[2]) | ((unsigned)f2bf(s[3]) << 16);
    pk.z = (unsigned)f2bf(s[4]) | ((unsigned)f2bf(s[5]) << 16);
    pk.w = (unsigned)f2bf(s[6]) | ((unsigned)f2bf(s[7]) << 16);
    const unsigned unit = (((unsigned)(ob * 32 + ks) * 4u + (unsigned)nf) << 6) +
                          (unsigned)(hi * 16 + lo);
    *(uint4*)(wq + ((size_t)unit << 3)) = pk;
  }
}

// Dense GEMM: out = x @ Wq^T + bias2.  WG = 64 tokens x all 1024 outs.
// A-tile: bf16 [64][1024] in LDS, row-swizzled (byte ^= (row&15)<<4).
// B: fragment-major from L2 (coalesced 1 KiB wave-loads). Two N-half passes.
__global__ __launch_bounds__(THREADS, 2)
void bsl_main(const float* __restrict__ x,
              const unsigned char* __restrict__ ws,
              float* __restrict__ out) {
  extern __shared__ unsigned char lds[];

  const int tid = threadIdx.x;
  const int lane = tid & 63;
  const int wv = tid >> 6;   // 0..7
  const int lo = lane & 15;
  const int hi = lane >> 4;
  const size_t row0 = (size_t)blockIdx.x * TM;

  // ---- stage: convert x tile fp32 -> bf16 LDS (coalesced, no gather) ----
  {
    const float* xq = x + row0 * D_DIM;
    const int rbase = tid >> 7;        // 0..3
    const int j0 = (tid & 127) * 8;    // 8 consecutive cols
    #pragma unroll
    for (int q = 0; q < 16; ++q) {
      const int row = (q << 2) + rbase;
      const float4 v0 = *(const float4*)(xq + (size_t)row * D_DIM + j0);
      const float4 v1 = *(const float4*)(xq + (size_t)row * D_DIM + j0 + 4);
      uint4 pk;
      pk.x = (unsigned)f2bf(v0.x) | ((unsigned)f2bf(v0.y) << 16);
      pk.y = (unsigned)f2bf(v0.z) | ((unsigned)f2bf(v0.w) << 16);
      pk.z = (unsigned)f2bf(v1.x) | ((unsigned)f2bf(v1.y) << 16);
      pk.w = (unsigned)f2bf(v1.z) | ((unsigned)f2bf(v1.w) << 16);
      *(uint4*)(lds + (unsigned)row * 2048u +
                (((unsigned)(j0 * 2)) ^ (((unsigned)row & 15u) << 4))) = pk;
    }
  }
  __syncthreads();

  const unsigned short* wq = (const unsigned short*)(ws + WS_WQ);
  const float* bias2 = (const float*)(ws + WS_BIAS2);

  #pragma unroll 1
  for (int h = 0; h < 2; ++h) {
    f32x4 acc[4][4];
    {
      const f32x4 z = {0.0f, 0.0f, 0.0f, 0.0f};
      #pragma unroll
      for (int mf = 0; mf < 4; ++mf)
        #pragma unroll
        for (int nf = 0; nf < 4; ++nf)
          acc[mf][nf] = z;
    }

    const int ob = (h << 3) + wv;  // out block 0..15
    const unsigned short* wqb = wq + ((size_t)ob << 16);  // ob * 32*4*64*8 ushorts

    #pragma unroll 4
    for (int ks = 0; ks < 32; ++ks) {
      short8 a[4];
      #pragma unroll
      for (int mf = 0; mf < 4; ++mf) {
        const unsigned row = (unsigned)((mf << 4) + lo);
        a[mf] = *(const short8*)(lds + row * 2048u +
                 (((unsigned)((ks << 6) + (hi << 4))) ^ ((unsigned)lo << 4)));
      }
      short8 b[4];
      #pragma unroll
      for (int nf = 0; nf < 4; ++nf)
        b[nf] = *(const short8*)(wqb + ((size_t)((((ks << 2) + nf) << 6) + lane) << 3));
      #pragma unroll
      for (int mf = 0; mf < 4; ++mf)
        #pragma unroll
        for (int nf = 0; nf < 4; ++nf)
          acc[mf][nf] = __builtin_amdgcn_mfma_f32_16x16x32_bf16(a[mf], b[nf], acc[mf][nf], 0, 0, 0);
    }

    // ---- epilogue: direct fp32 stores + bias2 ----
    const int colbase = (h << 9) + (wv << 6);
    float bv[4];
    #pragma unroll
    for (int nf = 0; nf < 4; ++nf) bv[nf] = bias2[colbase + (nf << 4) + lo];
    #pragma unroll
    for (int mf = 0; mf < 4; ++mf)
      #pragma unroll
      for (int nf = 0; nf < 4; ++nf)
        #pragma unroll
        for (int reg = 0; reg < 4; ++reg) {
          const int trow = (mf << 4) + (hi << 2) + reg;
          out[(row0 + (unsigned)trow) * D_DIM + colbase + (nf << 4) + lo] =
              acc[mf][nf][reg] + bv[nf];
        }
  }
}

extern "C" void kernel_launch(void* const* d_in, const int* in_sizes, int n_in,
                              void* d_out, int out_size, void* d_ws, size_t ws_size,
                              hipStream_t stream) {
  const float* x = (const float*)d_in[0];
  const int* in_perm = (const int*)d_in[1];
  const int* out_perm = (const int*)d_in[2];
  const float* wblocks = (const float*)d_in[3];
  const int* brow = (const int*)d_in[4];
  const int* bcol = (const int*)d_in[5];
  const float* bias = (const float*)d_in[6];
  float* out = (float*)d_out;
  unsigned char* ws = (unsigned char*)d_ws;

  // allow 128 KiB dynamic LDS (idempotent, host-side, capture-safe)
  hipFuncSetAttribute((const void*)bsl_main,
                      hipFuncAttributeMaxDynamicSharedMemorySize, LDS_BYTES);

  prep_wq<<<1024, 256, 0, stream>>>(wblocks, brow, bcol, in_perm, out_perm, bias, ws);
  bsl_main<<<NTILES, THREADS, LDS_BYTES, stream>>>(x, ws, out);
}